// Round 1
// baseline (9813.940 us; speedup 1.0000x reference)
//
#include <hip/hip_runtime.h>
#include <stdint.h>

typedef _Float16 f16x8 __attribute__((ext_vector_type(8)));
typedef unsigned short u16x8 __attribute__((ext_vector_type(8)));
typedef float f32x4 __attribute__((ext_vector_type(4)));

#define MFMA16(a,b,c) __builtin_amdgcn_mfma_f32_16x16x32_f16((a),(b),(c),0,0,0)

// problem dims
#define LSEQ 256
#define H0N  269   // N_INTER
#define H1N  179   // N_COMMAND
#define H2N  64    // N_MOTOR
#define H0P  272   // padded
#define H1P  192
#define K0REAL 333 // 64 + 269
#define K1REAL 448 // 269 + 179
#define K2REAL 243 // 179 + 64
#define KK0  11    // K0 padded to 352
#define KK1  15    // K1 layout [a:272|h1:192] padded to 480
#define KK2  8     // K2 layout [b:192|c:64] = 256
#define XH0S 360   // 352 + 8 pad (bank spread)
#define XH1S 488
#define XH2S 264
#define MR   32    // batch rows per group

// ws layout per group (bytes)
#define H0_OFF   0
#define H1_OFF   34816
#define C2_OFF   59392
#define CNT_OFF  67584
#define GSTRIDE  (80*1024)

__device__ __forceinline__ unsigned short f2h_bits(float v) {
  return __builtin_bit_cast(unsigned short, (_Float16)v);
}

__device__ __forceinline__ void wait_ge(unsigned int* p, unsigned int tgt) {
  for (int i = 0; i < (1 << 18); ++i) {   // bounded spin: no hang on protocol bug
    unsigned int v = __hip_atomic_load(p, __ATOMIC_ACQUIRE, __HIP_MEMORY_SCOPE_AGENT);
    if (v >= tgt) return;
    __builtin_amdgcn_s_sleep(4);
  }
}

__device__ __forceinline__ void inc_cnt(unsigned int* p) {
  __hip_atomic_fetch_add(p, 1u, __ATOMIC_RELEASE, __HIP_MEMORY_SCOPE_AGENT);
}

// ---------------- init: zero state+counters, load hidden_state ----------------
__global__ void __launch_bounds__(256) init_state(const float* __restrict__ hs, char* __restrict__ ws) {
  int g = blockIdx.x, tid = threadIdx.x;
  char* gb = ws + (size_t)g * GSTRIDE;
  unsigned short* H0 = (unsigned short*)(gb + H0_OFF);
  unsigned short* H1 = (unsigned short*)(gb + H1_OFF);
  unsigned short* C2 = (unsigned short*)(gb + C2_OFF);
  unsigned short* base = (unsigned short*)gb;
  for (int i = tid; i < 33792; i += 256) base[i] = 0;   // H0/H1/C2 both parities
  if (tid < 3) *(unsigned int*)(gb + CNT_OFF + 64*tid) = 0u;
  __syncthreads();
  int b0 = g * MR;
  for (int i = tid; i < MR*H0N; i += 256) { int r = i/H0N, c = i%H0N; H0[r*H0P + c] = f2h_bits(hs[(size_t)(b0+r)*512 + c]); }
  for (int i = tid; i < MR*H1N; i += 256) { int r = i/H1N, c = i%H1N; H1[r*H1P + c] = f2h_bits(hs[(size_t)(b0+r)*512 + H0N + c]); }
  for (int i = tid; i < MR*64;  i += 256) { int r = i>>6,  c = i&63;  C2[r*64 + c]  = f2h_bits(hs[(size_t)(b0+r)*512 + 448 + c]); }
}

// ---------------- weight fragment builder (B operand, K x 16 tile) ----------------
// B[k][col] = Weff[gate*h + col][wc(k)], masked for gates 0,1. wc maps padded xh index -> real col.
template<int KK, int MODE>
__device__ __forceinline__ void build_frag(f16x8* wf, const float* __restrict__ W, const float* __restrict__ Msk,
                                           int h, int Kreal, int gate, int tile, int lane) {
  int col = tile * 16 + (lane & 15);
  bool nv = (col < h);
  #pragma unroll
  for (int kk = 0; kk < KK; ++kk) {
    f16x8 s;
    #pragma unroll
    for (int e = 0; e < 8; ++e) {
      int k = kk*32 + ((lane >> 4) << 3) + e;
      int wc;
      if (MODE == 0)      wc = (k < 333) ? k : -1;                                  // [x64|h269]
      else if (MODE == 1) wc = (k < 269) ? k : ((k >= 272 && k < 451) ? (k - 3) : -1);  // [a272|h1 192]
      else                wc = (k < 179) ? k : ((k >= 192 && k < 256) ? (k - 13) : -1); // [b192|c64]
      float val = 0.f;
      if (nv && wc >= 0) {
        val = W[(size_t)(gate * h + col) * Kreal + wc];
        if (gate < 2) val *= Msk[(size_t)col * Kreal + wc];
      }
      s[e] = (_Float16)val;
    }
    wf[kk] = s;
  }
}

__device__ __forceinline__ f16x8 lda(const unsigned short* xh, int stride, int mt, int kk, int lane) {
  const unsigned short* p = xh + (size_t)(mt*16 + (lane & 15)) * stride + kk*32 + ((lane >> 4) << 3);
  return __builtin_bit_cast(f16x8, *(const u16x8*)p);
}

// ---------------- xh staging ----------------
__device__ __forceinline__ void build_xh0(unsigned short* xh, const float* __restrict__ dt, int b0, int t,
                                          const unsigned short* H0cur, int tid) {
  { // x_t: 32 rows x 64 f32 -> f16
    int row = tid >> 3, c = (tid & 7) * 8;
    const float* src = dt + ((size_t)(b0 + row) * LSEQ + t) * 64 + c;
    float4 fa = *(const float4*)src;
    float4 fb = *(const float4*)(src + 4);
    unsigned short* d = xh + (size_t)row * XH0S + c;
    d[0]=f2h_bits(fa.x); d[1]=f2h_bits(fa.y); d[2]=f2h_bits(fa.z); d[3]=f2h_bits(fa.w);
    d[4]=f2h_bits(fb.x); d[5]=f2h_bits(fb.y); d[6]=f2h_bits(fb.z); d[7]=f2h_bits(fb.w);
  }
  for (int idx = tid; idx < MR*34; idx += 256) {   // h0: 272 wide
    int r = idx / 34, c8 = (idx % 34) * 8;
    *(u16x8*)(xh + (size_t)r*XH0S + 64 + c8) = *(const u16x8*)(H0cur + (size_t)r*H0P + c8);
  }
  u16x8 zz = {0,0,0,0,0,0,0,0};
  for (int idx = tid; idx < MR*2; idx += 256) {    // k-pad 336..351
    int r = idx >> 1, c8 = 336 + (idx & 1)*8;
    *(u16x8*)(xh + (size_t)r*XH0S + c8) = zz;
  }
}

__device__ __forceinline__ void build_xh1(unsigned short* xh, const unsigned short* Acur,
                                          const unsigned short* H1cur, int tid) {
  for (int idx = tid; idx < MR*34; idx += 256) {
    int r = idx/34, c8 = (idx%34)*8;
    *(u16x8*)(xh + (size_t)r*XH1S + c8) = *(const u16x8*)(Acur + (size_t)r*H0P + c8);
  }
  for (int idx = tid; idx < MR*24; idx += 256) {
    int r = idx/24, c8 = (idx%24)*8;
    *(u16x8*)(xh + (size_t)r*XH1S + 272 + c8) = *(const u16x8*)(H1cur + (size_t)r*H1P + c8);
  }
  u16x8 zz = {0,0,0,0,0,0,0,0};
  for (int idx = tid; idx < MR*2; idx += 256) {    // k-pad 464..479
    int r = idx >> 1, c8 = 464 + (idx & 1)*8;
    *(u16x8*)(xh + (size_t)r*XH1S + c8) = zz;
  }
}

__device__ __forceinline__ void build_xh2(unsigned short* xh, const unsigned short* Bcur,
                                          const unsigned short* Ccur, int tid) {
  for (int idx = tid; idx < MR*24; idx += 256) {
    int r = idx/24, c8 = (idx%24)*8;
    *(u16x8*)(xh + (size_t)r*XH2S + c8) = *(const u16x8*)(Bcur + (size_t)r*H1P + c8);
  }
  for (int idx = tid; idx < MR*8; idx += 256) {
    int r = idx >> 3, c8 = (idx & 7)*8;
    *(u16x8*)(xh + (size_t)r*XH2S + 192 + c8) = *(const u16x8*)(Ccur + (size_t)r*64 + c8);
  }
}

// ---------------- one cell: MFMA all 4 gates (gate = wave), combine, write h_next ----------------
template<int KK, int NT>
__device__ __forceinline__ void cell_phase(const unsigned short* xh, int xstride,
    const f16x8 (&wf)[NT][KK], int ntact, const int* tids, int h,
    const float* biasL, unsigned short* Hnext, int hstride,
    float* zbuf, int lane, int wave, int tid) {
  #pragma unroll
  for (int it = 0; it < NT; ++it) {
    if (it < ntact) {
      f32x4 acc0 = {0.f,0.f,0.f,0.f}, acc1 = {0.f,0.f,0.f,0.f};
      #pragma unroll
      for (int kk = 0; kk < KK; ++kk) {
        f16x8 a0 = lda(xh, xstride, 0, kk, lane);
        f16x8 a1 = lda(xh, xstride, 1, kk, lane);
        acc0 = MFMA16(a0, wf[it][kk], acc0);
        acc1 = MFMA16(a1, wf[it][kk], acc1);
      }
      int colz = lane & 15, rb = (lane >> 4) * 4;
      #pragma unroll
      for (int r = 0; r < 4; ++r) {
        zbuf[(wave*32 + rb + r)*16 + colz]      = acc0[r];
        zbuf[(wave*32 + 16 + rb + r)*16 + colz] = acc1[r];
      }
    }
    __syncthreads();
    if (it < ntact) {
      int tile = tids[it];
      #pragma unroll
      for (int q = 0; q < 2; ++q) {
        int e = tid + q*256;
        int row = e >> 4, cc = e & 15;
        int n = tile*16 + cc;
        if (n < h) {
          float ff1 = zbuf[(0*32+row)*16+cc] + biasL[it*64 + cc];
          float ff2 = zbuf[(1*32+row)*16+cc] + biasL[it*64 + 16 + cc];
          float ta  = zbuf[(2*32+row)*16+cc] + biasL[it*64 + 32 + cc];
          float tb  = zbuf[(3*32+row)*16+cc] + biasL[it*64 + 48 + cc];
          float ti  = 1.f / (1.f + __expf(-(ta + tb)));
          float hv  = tanhf(ff1)*(1.f - ti) + ti*tanhf(ff2);
          Hnext[(size_t)row*hstride + n] = f2h_bits(hv);
        }
      }
    }
    __syncthreads();
  }
}

// ---------------- output projection y_{tq} = c_{tq} @ Wout^T + bout ----------------
__device__ __forceinline__ void yproj(const unsigned short* Cb, const f16x8 (&wf)[2], float boutv,
                                      float* __restrict__ out, int b0, int tq, int ytile, int lane, int wave) {
  if (wave > 1) return;
  int mt = wave;
  f32x4 acc = {0.f,0.f,0.f,0.f};
  #pragma unroll
  for (int kk = 0; kk < 2; ++kk) {
    const unsigned short* p = Cb + (size_t)(mt*16 + (lane & 15)) * 64 + kk*32 + ((lane >> 4) << 3);
    f16x8 a = __builtin_bit_cast(f16x8, *(const u16x8*)p);
    acc = MFMA16(a, wf[kk], acc);
  }
  int cc = lane & 15, rb = (lane >> 4) * 4;
  #pragma unroll
  for (int r = 0; r < 4; ++r) {
    int row = mt*16 + rb + r;
    out[((size_t)(b0 + row) * LSEQ + tq) * 64 + ytile*16 + cc] = acc[r] + boutv;
  }
}

// ---------------- persistent recurrence kernel ----------------
__global__ void __launch_bounds__(256, 1) rnn_persist(
    const float* __restrict__ dt,
    const float* __restrict__ W0, const float* __restrict__ b0v,
    const float* __restrict__ W1, const float* __restrict__ b1v,
    const float* __restrict__ W2, const float* __restrict__ b2v,
    const float* __restrict__ Wout, const float* __restrict__ boutg,
    const float* __restrict__ M0, const float* __restrict__ M1, const float* __restrict__ M2,
    float* __restrict__ out, char* __restrict__ ws)
{
  __shared__ __attribute__((aligned(16))) unsigned short xh[MR * XH1S]; // 31232 B (reused all phases)
  __shared__ __attribute__((aligned(16))) float zbuf[4 * MR * 16];      // 8 KB
  __shared__ float biasL[256];

  int tid = threadIdx.x;
  int lane = tid & 63, wave = tid >> 6;
  int bid = blockIdx.x;
  int xcd = bid & 7, slot = bid >> 3;        // bid%8 ~ XCD (perf heuristic only)
  int g = (xcd << 1) | (slot >> 4);          // group 0..15 (16 WGs, same XCD)
  int j = slot & 15;                         // member 0..15
  int b0 = g * MR;                           // batch rows [b0, b0+32)

  char* gb = ws + (size_t)g * GSTRIDE;
  unsigned short* H0 = (unsigned short*)(gb + H0_OFF);   // [2][32][272]
  unsigned short* H1 = (unsigned short*)(gb + H1_OFF);   // [2][32][192]
  unsigned short* C2 = (unsigned short*)(gb + C2_OFF);   // [2][32][64]
  unsigned int* c0p = (unsigned int*)(gb + CNT_OFF);
  unsigned int* c1p = (unsigned int*)(gb + CNT_OFF + 64);
  unsigned int* c2p = (unsigned int*)(gb + CNT_OFF + 128);

  if (j < 12) {
    // ---- cell0 tile j, cell1 tile j ----
    f16x8 w0f[1][KK0], w1f[1][KK1];
    build_frag<KK0,0>(w0f[0], W0, M0, H0N, K0REAL, wave, j, lane);
    build_frag<KK1,1>(w1f[0], W1, M1, H1N, K1REAL, wave, j, lane);
    {
      int ii = tid;
      if (ii < 128) {
        int half = ii >> 6, gg = (ii >> 4) & 3, cc = ii & 15;
        float v = 0.f;
        int n = j*16 + cc;
        if (half == 0) { if (n < H0N) v = b0v[gg*H0N + n]; }
        else           { if (n < H1N) v = b1v[gg*H1N + n]; }
        biasL[ii] = v;
      }
    }
    __syncthreads();
    int t0ids[1] = { j };
    int t1ids[1] = { j };
    for (int t = 0; t < LSEQ; ++t) {
      // phase0: a_t = cell0(x_t, a_{t-1})
      if (tid == 0) wait_ge(c0p, 16u*t);
      __syncthreads();
      build_xh0(xh, dt, b0, t, H0 + (size_t)(t & 1)*MR*H0P, tid);
      __syncthreads();
      cell_phase<KK0,1>(xh, XH0S, w0f, 1, t0ids, H0N, biasL,
                        H0 + (size_t)((t+1) & 1)*MR*H0P, H0P, zbuf, lane, wave, tid);
      if (tid == 0) inc_cnt(c0p);
      // phase1: b_t = cell1(a_t, b_{t-1})
      if (tid == 0) { wait_ge(c0p, 16u*(t+1)); wait_ge(c1p, 12u*t); }
      __syncthreads();
      build_xh1(xh, H0 + (size_t)((t+1) & 1)*MR*H0P, H1 + (size_t)(t & 1)*MR*H1P, tid);
      __syncthreads();
      cell_phase<KK1,1>(xh, XH1S, w1f, 1, t1ids, H1N, biasL + 64,
                        H1 + (size_t)((t+1) & 1)*MR*H1P, H1P, zbuf, lane, wave, tid);
      if (tid == 0) inc_cnt(c1p);
    }
  } else {
    // ---- j=12: cell0 tiles {12,16} + y-tile 0; j=13: cell0 {13} + cell2 {0,1} + y1;
    //      j=14: cell0 {14} + cell2 {2} + y2;  j=15: cell0 {15} + cell2 {3} + y3 ----
    int nt0 = (j == 12) ? 2 : 1;
    int t0ids[2] = { j, 16 };
    int nt2 = (j == 13) ? 2 : ((j >= 14) ? 1 : 0);
    int t2ids[2] = { (j == 13) ? 0 : ((j == 14) ? 2 : 3), 1 };
    int ytile = j - 12;
    f16x8 w0f[2][KK0], w2f[2][KK2], woutf[2];
    build_frag<KK0,0>(w0f[0], W0, M0, H0N, K0REAL, wave, t0ids[0], lane);
    build_frag<KK0,0>(w0f[1], W0, M0, H0N, K0REAL, wave, t0ids[1], lane);
    build_frag<KK2,2>(w2f[0], W2, M2, H2N, K2REAL, wave, t2ids[0], lane);
    build_frag<KK2,2>(w2f[1], W2, M2, H2N, K2REAL, wave, t2ids[1], lane);
    {
      int wcol = ytile*16 + (lane & 15);
      #pragma unroll
      for (int kk = 0; kk < 2; ++kk) {
        f16x8 s;
        #pragma unroll
        for (int e = 0; e < 8; ++e) {
          int k = kk*32 + ((lane >> 4) << 3) + e;
          s[e] = (_Float16)Wout[(size_t)wcol*64 + k];
        }
        woutf[kk] = s;
      }
    }
    float bov = boutg[ytile*16 + (lane & 15)];
    {
      int ii = tid;
      float v = 0.f;
      if (ii < 128) {
        int it = ii >> 6, gg = (ii >> 4) & 3, cc = ii & 15;
        if (it < nt0) { int n = t0ids[it]*16 + cc; if (n < H0N) v = b0v[gg*H0N + n]; }
      } else {
        int i2 = ii - 128; int it = i2 >> 6, gg = (i2 >> 4) & 3, cc = i2 & 15;
        if (it < nt2) { int n = t2ids[it]*16 + cc; v = b2v[gg*H2N + n]; }
      }
      biasL[ii] = v;
    }
    __syncthreads();
    for (int t = 0; t < LSEQ; ++t) {
      // phase0
      if (tid == 0) wait_ge(c0p, 16u*t);
      __syncthreads();
      build_xh0(xh, dt, b0, t, H0 + (size_t)(t & 1)*MR*H0P, tid);
      __syncthreads();
      cell_phase<KK0,2>(xh, XH0S, w0f, nt0, t0ids, H0N, biasL,
                        H0 + (size_t)((t+1) & 1)*MR*H0P, H0P, zbuf, lane, wave, tid);
      if (tid == 0) inc_cnt(c0p);
      // phase2: c_t = cell2(b_t, c_{t-1}); also y_{t-1}
      if (j == 12) {
        if (tid == 0) wait_ge(c2p, 3u*t);
        __syncthreads();
        if (t > 0) yproj(C2 + (size_t)(t & 1)*MR*64, woutf, bov, out, b0, t-1, ytile, lane, wave);
      } else {
        if (tid == 0) { wait_ge(c1p, 12u*(t+1)); wait_ge(c2p, 3u*t); }
        __syncthreads();
        build_xh2(xh, H1 + (size_t)((t+1) & 1)*MR*H1P, C2 + (size_t)(t & 1)*MR*64, tid);
        __syncthreads();
        cell_phase<KK2,2>(xh, XH2S, w2f, nt2, t2ids, H2N, biasL + 128,
                          C2 + (size_t)((t+1) & 1)*MR*64, 64, zbuf, lane, wave, tid);
        if (tid == 0) inc_cnt(c2p);
        if (t > 0) yproj(C2 + (size_t)(t & 1)*MR*64, woutf, bov, out, b0, t-1, ytile, lane, wave);
      }
    }
    // tail: y_{255} from C2 parity (256&1)==0
    if (tid == 0) wait_ge(c2p, 3u*LSEQ);
    __syncthreads();
    yproj(C2, woutf, bov, out, b0, LSEQ-1, ytile, lane, wave);
  }
}

extern "C" void kernel_launch(void* const* d_in, const int* in_sizes, int n_in,
                              void* d_out, int out_size, void* d_ws, size_t ws_size,
                              hipStream_t stream) {
  const float* dt   = (const float*)d_in[0];
  const float* hs   = (const float*)d_in[1];
  const float* W0   = (const float*)d_in[2];
  const float* b0v  = (const float*)d_in[3];
  const float* W1   = (const float*)d_in[4];
  const float* b1v  = (const float*)d_in[5];
  const float* W2   = (const float*)d_in[6];
  const float* b2v  = (const float*)d_in[7];
  const float* Wo   = (const float*)d_in[8];
  const float* bo   = (const float*)d_in[9];
  const float* M0   = (const float*)d_in[10];
  const float* M1   = (const float*)d_in[11];
  const float* M2   = (const float*)d_in[12];
  (void)in_sizes; (void)n_in; (void)out_size; (void)ws_size;
  init_state<<<16, 256, 0, stream>>>(hs, (char*)d_ws);
  rnn_persist<<<256, 256, 0, stream>>>(dt, W0, b0v, W1, b1v, W2, b2v, Wo, bo, M0, M1, M2,
                                       (float*)d_out, (char*)d_ws);
}

// Round 2
// 2172.406 us; speedup vs baseline: 4.5175x; 4.5175x over previous
//
#include <hip/hip_runtime.h>
#include <stdint.h>

typedef _Float16 f16x8 __attribute__((ext_vector_type(8)));
typedef unsigned short u16x8 __attribute__((ext_vector_type(8)));
typedef float f32x4 __attribute__((ext_vector_type(4)));
typedef unsigned long long u64t;

#define MFMA16(a,b,c) __builtin_amdgcn_mfma_f32_16x16x32_f16((a),(b),(c),0,0,0)

// problem dims
#define LSEQ 256
#define H0N  269   // N_INTER
#define H1N  179   // N_COMMAND
#define H2N  64    // N_MOTOR
#define H0P  272   // padded
#define H1P  192
#define K0REAL 333 // 64 + 269
#define K1REAL 448 // 269 + 179
#define K2REAL 243 // 179 + 64
#define KK0  11    // K0 padded to 352
#define KK1  15    // K1 layout [a:272|h1:192] padded to 480
#define KK2  8     // K2 layout [b:192|c:64] = 256
#define XH0S 360
#define XH1S 488
#define XH2S 264
#define MR   32    // batch rows per group

// ws layout per group (bytes)
#define H0_OFF   0
#define H1_OFF   34816
#define C2_OFF   59392
#define CNT_OFF  67584
#define GSTRIDE  (80*1024)

__device__ __forceinline__ unsigned short f2h_bits(float v) {
  return __builtin_bit_cast(unsigned short, (_Float16)v);
}

// ---- cache-bypassing (coherence-point) data movement: relaxed agent atomics ----
// No acquire/release anywhere -> no L2 writeback/invalidate storms. Visibility is
// guaranteed because every cross-WG datum travels via sc-flagged ops that are
// coherent at the point of coherency regardless of XCD placement.
__device__ __forceinline__ u16x8 ldg16_sc(const unsigned short* p) {
  const u64t* q = (const u64t*)p;
  u64t a = __hip_atomic_load(q,     __ATOMIC_RELAXED, __HIP_MEMORY_SCOPE_AGENT);
  u64t b = __hip_atomic_load(q + 1, __ATOMIC_RELAXED, __HIP_MEMORY_SCOPE_AGENT);
  union { u64t d[2]; u16x8 v; } u; u.d[0] = a; u.d[1] = b; return u.v;
}
__device__ __forceinline__ void stg_h_sc(unsigned short* p, unsigned short v) {
  __hip_atomic_store(p, v, __ATOMIC_RELAXED, __HIP_MEMORY_SCOPE_AGENT);
}
__device__ __forceinline__ unsigned int ld_cnt(const unsigned int* p) {
  return __hip_atomic_load(p, __ATOMIC_RELAXED, __HIP_MEMORY_SCOPE_AGENT);
}
__device__ __forceinline__ void wait_ge(const unsigned int* p, unsigned int tgt) {
  for (int i = 0; i < (1 << 18); ++i) {   // bounded spin: no hang on protocol bug
    if (ld_cnt(p) >= tgt) return;
    __builtin_amdgcn_s_sleep(2);
  }
}
// publish: caller guarantees prior stores drained (post-__syncthreads, or own stores)
__device__ __forceinline__ void bump(unsigned int* p) {
  asm volatile("s_waitcnt vmcnt(0)" ::: "memory");
  __hip_atomic_fetch_add(p, 1u, __ATOMIC_RELAXED, __HIP_MEMORY_SCOPE_AGENT);
}

// ---------------- init: zero state+counters, load hidden_state ----------------
__global__ void __launch_bounds__(256) init_state(const float* __restrict__ hs, char* __restrict__ ws) {
  int g = blockIdx.x, tid = threadIdx.x;
  char* gb = ws + (size_t)g * GSTRIDE;
  unsigned short* H0 = (unsigned short*)(gb + H0_OFF);
  unsigned short* H1 = (unsigned short*)(gb + H1_OFF);
  unsigned short* C2 = (unsigned short*)(gb + C2_OFF);
  unsigned short* base = (unsigned short*)gb;
  for (int i = tid; i < 33792; i += 256) base[i] = 0;   // H0/H1/C2 both parities
  if (tid < 4) *(unsigned int*)(gb + CNT_OFF + 256*tid) = 0u;
  __syncthreads();
  int b0 = g * MR;
  for (int i = tid; i < MR*H0N; i += 256) { int r = i/H0N, c = i%H0N; H0[r*H0P + c] = f2h_bits(hs[(size_t)(b0+r)*512 + c]); }
  for (int i = tid; i < MR*H1N; i += 256) { int r = i/H1N, c = i%H1N; H1[r*H1P + c] = f2h_bits(hs[(size_t)(b0+r)*512 + H0N + c]); }
  for (int i = tid; i < MR*64;  i += 256) { int r = i>>6,  c = i&63;  C2[r*64 + c]  = f2h_bits(hs[(size_t)(b0+r)*512 + 448 + c]); }
}

// ---------------- weight fragment builder (B operand, K x 16 tile) ----------------
template<int KK, int MODE>
__device__ __forceinline__ void build_frag(f16x8* wf, const float* __restrict__ W, const float* __restrict__ Msk,
                                           int h, int Kreal, int gate, int tile, int lane) {
  int col = tile * 16 + (lane & 15);
  bool nv = (col < h);
  #pragma unroll
  for (int kk = 0; kk < KK; ++kk) {
    f16x8 s;
    #pragma unroll
    for (int e = 0; e < 8; ++e) {
      int k = kk*32 + ((lane >> 4) << 3) + e;
      int wc;
      if (MODE == 0)      wc = (k < 333) ? k : -1;                                  // [x64|h269]
      else if (MODE == 1) wc = (k < 269) ? k : ((k >= 272 && k < 451) ? (k - 3) : -1);  // [a272|h1 192]
      else                wc = (k < 179) ? k : ((k >= 192 && k < 256) ? (k - 13) : -1); // [b192|c64]
      float val = 0.f;
      if (nv && wc >= 0) {
        val = W[(size_t)(gate * h + col) * Kreal + wc];
        if (gate < 2) val *= Msk[(size_t)col * Kreal + wc];
      }
      s[e] = (_Float16)val;
    }
    wf[kk] = s;
  }
}

__device__ __forceinline__ f16x8 lda(const unsigned short* xh, int stride, int mt, int kk, int lane) {
  const unsigned short* p = xh + (size_t)(mt*16 + (lane & 15)) * stride + kk*32 + ((lane >> 4) << 3);
  return __builtin_bit_cast(f16x8, *(const u16x8*)p);
}

// ---------------- xh staging (state reads via sc-loads) ----------------
__device__ __forceinline__ void build_xh0(unsigned short* xh, const float* __restrict__ dt, int b0, int t,
                                          const unsigned short* H0cur, int tid) {
  { // x_t: 32 rows x 64 f32 -> f16
    int row = tid >> 3, c = (tid & 7) * 8;
    const float* src = dt + ((size_t)(b0 + row) * LSEQ + t) * 64 + c;
    float4 fa = *(const float4*)src;
    float4 fb = *(const float4*)(src + 4);
    unsigned short* d = xh + (size_t)row * XH0S + c;
    d[0]=f2h_bits(fa.x); d[1]=f2h_bits(fa.y); d[2]=f2h_bits(fa.z); d[3]=f2h_bits(fa.w);
    d[4]=f2h_bits(fb.x); d[5]=f2h_bits(fb.y); d[6]=f2h_bits(fb.z); d[7]=f2h_bits(fb.w);
  }
  for (int idx = tid; idx < MR*34; idx += 256) {   // h0: 272 wide
    int r = idx / 34, c8 = (idx % 34) * 8;
    *(u16x8*)(xh + (size_t)r*XH0S + 64 + c8) = ldg16_sc(H0cur + (size_t)r*H0P + c8);
  }
  u16x8 zz = {0,0,0,0,0,0,0,0};
  for (int idx = tid; idx < MR*2; idx += 256) {    // k-pad 336..351
    int r = idx >> 1, c8 = 336 + (idx & 1)*8;
    *(u16x8*)(xh + (size_t)r*XH0S + c8) = zz;
  }
}

__device__ __forceinline__ void build_xh1(unsigned short* xh, const unsigned short* Acur,
                                          const unsigned short* H1cur, int tid) {
  for (int idx = tid; idx < MR*34; idx += 256) {
    int r = idx/34, c8 = (idx%34)*8;
    *(u16x8*)(xh + (size_t)r*XH1S + c8) = ldg16_sc(Acur + (size_t)r*H0P + c8);
  }
  for (int idx = tid; idx < MR*24; idx += 256) {
    int r = idx/24, c8 = (idx%24)*8;
    *(u16x8*)(xh + (size_t)r*XH1S + 272 + c8) = ldg16_sc(H1cur + (size_t)r*H1P + c8);
  }
  u16x8 zz = {0,0,0,0,0,0,0,0};
  for (int idx = tid; idx < MR*2; idx += 256) {    // k-pad 464..479
    int r = idx >> 1, c8 = 464 + (idx & 1)*8;
    *(u16x8*)(xh + (size_t)r*XH1S + c8) = zz;
  }
}

__device__ __forceinline__ void build_xh2(unsigned short* xh, const unsigned short* Bcur,
                                          const unsigned short* Ccur, int tid) {
  for (int idx = tid; idx < MR*24; idx += 256) {
    int r = idx/24, c8 = (idx%24)*8;
    *(u16x8*)(xh + (size_t)r*XH2S + c8) = ldg16_sc(Bcur + (size_t)r*H1P + c8);
  }
  for (int idx = tid; idx < MR*8; idx += 256) {
    int r = idx >> 3, c8 = (idx & 7)*8;
    *(u16x8*)(xh + (size_t)r*XH2S + 192 + c8) = ldg16_sc(Ccur + (size_t)r*64 + c8);
  }
}

// ---------------- one cell: MFMA all 4 gates (gate = wave), combine, write h_next ----------------
template<int KK, int NT>
__device__ __forceinline__ void cell_phase(const unsigned short* xh, int xstride,
    const f16x8 (&wf)[NT][KK], int ntact, const int* tids, int h,
    const float* biasL, unsigned short* Hnext, int hstride,
    float* zbuf, int lane, int wave, int tid) {
  #pragma unroll
  for (int it = 0; it < NT; ++it) {
    if (it < ntact) {
      f32x4 acc0 = {0.f,0.f,0.f,0.f}, acc1 = {0.f,0.f,0.f,0.f};
      #pragma unroll
      for (int kk = 0; kk < KK; ++kk) {
        f16x8 a0 = lda(xh, xstride, 0, kk, lane);
        f16x8 a1 = lda(xh, xstride, 1, kk, lane);
        acc0 = MFMA16(a0, wf[it][kk], acc0);
        acc1 = MFMA16(a1, wf[it][kk], acc1);
      }
      int colz = lane & 15, rb = (lane >> 4) * 4;
      #pragma unroll
      for (int r = 0; r < 4; ++r) {
        zbuf[(wave*32 + rb + r)*16 + colz]      = acc0[r];
        zbuf[(wave*32 + 16 + rb + r)*16 + colz] = acc1[r];
      }
    }
    __syncthreads();
    if (it < ntact) {
      int tile = tids[it];
      #pragma unroll
      for (int q = 0; q < 2; ++q) {
        int e = tid + q*256;
        int row = e >> 4, cc = e & 15;
        int n = tile*16 + cc;
        if (n < h) {
          float ff1 = zbuf[(0*32+row)*16+cc] + biasL[it*64 + cc];
          float ff2 = zbuf[(1*32+row)*16+cc] + biasL[it*64 + 16 + cc];
          float ta  = zbuf[(2*32+row)*16+cc] + biasL[it*64 + 32 + cc];
          float tb  = zbuf[(3*32+row)*16+cc] + biasL[it*64 + 48 + cc];
          float ti  = 1.f / (1.f + __expf(-(ta + tb)));
          float hv  = tanhf(ff1)*(1.f - ti) + ti*tanhf(ff2);
          stg_h_sc(&Hnext[(size_t)row*hstride + n], f2h_bits(hv));
        }
      }
    }
    __syncthreads();   // drains each wave's vmcnt -> stores at coherence point
  }
}

// ---------------- output projection for step t (wave&1 = row-tile) ----------------
__device__ __forceinline__ void yproj2(const unsigned short* Cb, const f16x8 (&wf)[2], float boutv,
                                       float* __restrict__ out, int b0, int t, int ytile, int lane, int wave) {
  int mt = wave & 1;
  f32x4 acc = {0.f,0.f,0.f,0.f};
  #pragma unroll
  for (int kk = 0; kk < 2; ++kk) {
    f16x8 a = __builtin_bit_cast(f16x8, ldg16_sc(Cb + (size_t)(mt*16 + (lane & 15)) * 64 + kk*32 + ((lane >> 4) << 3)));
    acc = MFMA16(a, wf[kk], acc);
  }
  int cc = lane & 15, rb = (lane >> 4) * 4;
  #pragma unroll
  for (int r = 0; r < 4; ++r) {
    int row = mt*16 + rb + r;
    out[((size_t)(b0 + row) * LSEQ + t) * 64 + ytile*16 + cc] = acc[r] + boutv;
  }
}

// ---------------- persistent recurrence kernel ----------------
// WGs 0..13: cell0 (WGs 0..2 carry tiles 14..16 as a 2nd tile); WGs 0..11: cell1.
// WGs 14,15: cell2 (2 tiles each) + output projection (2 y-tiles each) — one
// phase behind, pipelined under the next step's phase0/phase1.
// Counters per step: c0p +=14, c1p +=12, c2w +=2 (C2 written), c2p +=2 (y done).
// Hazard guards:
//  - H0 slot reuse: phase0@t+2 overwrites a_t's slot; cell1 readers of a_t are
//    cell0 owners too, so c0p>=14(t+2) implies their phase1@t reads finished.
//  - H1 slot reuse: phase1@t overwrites b_{t-2}'s slot, read by cell2@(t-2):
//    guarded by c2w >= 2(t-1).
//  - C2 slot reuse: cell2@t overwrites c_{t-2}'s slot, read by xh2@(t-1)
//    (c2w>=2t) and y@(t-2) (c2p>=2(t-1)).
__global__ void __launch_bounds__(256, 1) rnn_persist(
    const float* __restrict__ dt,
    const float* __restrict__ W0, const float* __restrict__ b0v,
    const float* __restrict__ W1, const float* __restrict__ b1v,
    const float* __restrict__ W2, const float* __restrict__ b2v,
    const float* __restrict__ Wout, const float* __restrict__ boutg,
    const float* __restrict__ M0, const float* __restrict__ M1, const float* __restrict__ M2,
    float* __restrict__ out, char* __restrict__ ws)
{
  __shared__ __attribute__((aligned(16))) unsigned short xh[MR * XH1S]; // 31232 B
  __shared__ __attribute__((aligned(16))) float zbuf[4 * MR * 16];      // 8 KB
  __shared__ float biasL[256];

  int tid = threadIdx.x;
  int lane = tid & 63, wave = tid >> 6;
  int bid = blockIdx.x;
  int xcd = bid & 7, slot = bid >> 3;        // bid%8 ~ XCD (perf heuristic only)
  int g = (xcd << 1) | (slot >> 4);
  int j = slot & 15;
  int b0 = g * MR;

  char* gb = ws + (size_t)g * GSTRIDE;
  unsigned short* H0 = (unsigned short*)(gb + H0_OFF);
  unsigned short* H1 = (unsigned short*)(gb + H1_OFF);
  unsigned short* C2 = (unsigned short*)(gb + C2_OFF);
  unsigned int* c0p = (unsigned int*)(gb + CNT_OFF);
  unsigned int* c1p = (unsigned int*)(gb + CNT_OFF + 256);
  unsigned int* c2w = (unsigned int*)(gb + CNT_OFF + 512);
  unsigned int* c2p = (unsigned int*)(gb + CNT_OFF + 768);

  if (j <= 13) {
    int nt0 = (j < 3) ? 2 : 1;
    int t0ids[2] = { j, 14 + j };
    bool has1 = (j < 12);
    f16x8 w0f[2][KK0], w1f[1][KK1];
    build_frag<KK0,0>(w0f[0], W0, M0, H0N, K0REAL, wave, t0ids[0], lane);
    if (nt0 == 2) build_frag<KK0,0>(w0f[1], W0, M0, H0N, K0REAL, wave, t0ids[1], lane);
    if (has1)     build_frag<KK1,1>(w1f[0], W1, M1, H1N, K1REAL, wave, j, lane);
    {
      float v = 0.f;
      if (tid < 128) {
        int it = tid >> 6, gg = (tid >> 4) & 3, cc = tid & 15;
        if (it < nt0) { int n = t0ids[it]*16 + cc; if (n < H0N) v = b0v[gg*H0N + n]; }
      } else if (tid < 192 && has1) {
        int i2 = tid - 128, gg = (i2 >> 4) & 3, cc = i2 & 15;
        int n = j*16 + cc; if (n < H1N) v = b1v[gg*H1N + n];
      }
      if (tid < 192) biasL[tid] = v;
    }
    __syncthreads();
    int t1id[1] = { j };
    for (int t = 0; t < LSEQ; ++t) {
      // phase0: a_t = cell0(x_t, a_{t-1})
      if (tid == 0) wait_ge(c0p, 14u*t);
      __syncthreads();
      build_xh0(xh, dt, b0, t, H0 + (size_t)(t & 1)*MR*H0P, tid);
      __syncthreads();
      cell_phase<KK0,2>(xh, XH0S, w0f, nt0, t0ids, H0N, biasL,
                        H0 + (size_t)((t+1) & 1)*MR*H0P, H0P, zbuf, lane, wave, tid);
      if (tid == 0) bump(c0p);
      if (has1) {
        // phase1: b_t = cell1(a_t, b_{t-1})
        if (tid == 0) {
          wait_ge(c0p, 14u*(t+1));
          wait_ge(c1p, 12u*t);
          if (t >= 2) wait_ge(c2w, 2u*(t-1));   // H1 slot reuse vs cell2@(t-2)
        }
        __syncthreads();
        build_xh1(xh, H0 + (size_t)((t+1) & 1)*MR*H0P, H1 + (size_t)(t & 1)*MR*H1P, tid);
        __syncthreads();
        cell_phase<KK1,1>(xh, XH1S, w1f, 1, t1id, H1N, biasL + 128,
                          H1 + (size_t)((t+1) & 1)*MR*H1P, H1P, zbuf, lane, wave, tid);
        if (tid == 0) bump(c1p);
      }
    }
  } else {
    // ---- WGs 14,15: cell2 + y, one phase behind ----
    int t2ids[2] = { (j - 14)*2, (j - 14)*2 + 1 };
    int ytile = (j - 14)*2 + (wave >> 1);
    f16x8 w2f[2][KK2], woutf[2];
    build_frag<KK2,2>(w2f[0], W2, M2, H2N, K2REAL, wave, t2ids[0], lane);
    build_frag<KK2,2>(w2f[1], W2, M2, H2N, K2REAL, wave, t2ids[1], lane);
    {
      int wcol = ytile*16 + (lane & 15);
      #pragma unroll
      for (int kk = 0; kk < 2; ++kk) {
        f16x8 s;
        #pragma unroll
        for (int e = 0; e < 8; ++e) {
          int k = kk*32 + ((lane >> 4) << 3) + e;
          s[e] = (_Float16)Wout[(size_t)wcol*64 + k];
        }
        woutf[kk] = s;
      }
    }
    float bov = boutg[ytile*16 + (lane & 15)];
    if (tid < 128) {
      int it = tid >> 6, gg = (tid >> 4) & 3, cc = tid & 15;
      biasL[tid] = b2v[gg*H2N + t2ids[it]*16 + cc];
    }
    __syncthreads();
    for (int t = 0; t < LSEQ; ++t) {
      if (tid == 0) {
        wait_ge(c1p, 12u*(t+1));               // b_t ready
        if (t >= 1) { wait_ge(c2w, 2u*t); wait_ge(c2p, 2u*(t-1)); }  // C2 slot reuse
      }
      __syncthreads();
      build_xh2(xh, H1 + (size_t)((t+1) & 1)*MR*H1P, C2 + (size_t)(t & 1)*MR*64, tid);
      __syncthreads();
      cell_phase<KK2,2>(xh, XH2S, w2f, 2, t2ids, H2N, biasL,
                        C2 + (size_t)((t+1) & 1)*MR*64, 64, zbuf, lane, wave, tid);
      if (tid == 0) bump(c2w);
      if (tid == 0) wait_ge(c2w, 2u*(t+1));    // peer's half of c_t
      __syncthreads();
      yproj2(C2 + (size_t)((t+1) & 1)*MR*64, woutf, bov, out, b0, t, ytile, lane, wave);
      __syncthreads();
      if (tid == 0) bump(c2p);
    }
  }
}

extern "C" void kernel_launch(void* const* d_in, const int* in_sizes, int n_in,
                              void* d_out, int out_size, void* d_ws, size_t ws_size,
                              hipStream_t stream) {
  const float* dt   = (const float*)d_in[0];
  const float* hs   = (const float*)d_in[1];
  const float* W0   = (const float*)d_in[2];
  const float* b0v  = (const float*)d_in[3];
  const float* W1   = (const float*)d_in[4];
  const float* b1v  = (const float*)d_in[5];
  const float* W2   = (const float*)d_in[6];
  const float* b2v  = (const float*)d_in[7];
  const float* Wo   = (const float*)d_in[8];
  const float* bo   = (const float*)d_in[9];
  const float* M0   = (const float*)d_in[10];
  const float* M1   = (const float*)d_in[11];
  const float* M2   = (const float*)d_in[12];
  (void)in_sizes; (void)n_in; (void)out_size; (void)ws_size;
  init_state<<<16, 256, 0, stream>>>(hs, (char*)d_ws);
  rnn_persist<<<256, 256, 0, stream>>>(dt, W0, b0v, W1, b1v, W2, b2v, Wo, bo, M0, M1, M2,
                                       (float*)d_out, (char*)d_ws);
}

// Round 3
// 1641.138 us; speedup vs baseline: 5.9800x; 1.3237x over previous
//
#include <hip/hip_runtime.h>
#include <stdint.h>

typedef _Float16 f16x8 __attribute__((ext_vector_type(8)));
typedef unsigned short u16x8 __attribute__((ext_vector_type(8)));
typedef float f32x4 __attribute__((ext_vector_type(4)));
typedef unsigned long long u64t;

#define MFMA16(a,b,c) __builtin_amdgcn_mfma_f32_16x16x32_f16((a),(b),(c),0,0,0)

// problem dims
#define LSEQ 256
#define H0N  269   // N_INTER
#define H1N  179   // N_COMMAND
#define H2N  64    // N_MOTOR
#define H0P  272   // padded
#define H1P  192
#define K0REAL 333 // 64 + 269
#define K1REAL 448 // 269 + 179
#define K2REAL 243 // 179 + 64
#define KK0  11    // K0 padded to 352
#define KK1  15    // K1 layout [a:272|h1:192] padded to 480
#define KK2  8     // K2 layout [b:192|c:64] = 256
#define XH0S 360
#define XH1S 488
#define XH2S 264
#define MR   32    // batch rows per group

// rings
#define D0   8     // H0 history depth
#define D1   8     // H1 history depth
#define D2   4     // C2 history depth

// ws layout per group (bytes)
#define H0_OFF   0
#define H0_SLOT  (MR*H0P*2)            // 17408
#define H1_OFF   (D0*H0_SLOT)          // 139264
#define H1_SLOT  (MR*H1P*2)            // 12288
#define C2_OFF   (H1_OFF + D1*H1_SLOT) // 237568
#define C2_SLOT  (MR*64*2)             // 4096
#define CNT_OFF  (C2_OFF + D2*C2_SLOT) // 253952
#define GSTRIDE  262144                // 256 KiB

__device__ __forceinline__ unsigned short f2h_bits(float v) {
  return __builtin_bit_cast(unsigned short, (_Float16)v);
}

// ---- cache-bypassing (coherence-point) data movement: relaxed agent atomics ----
__device__ __forceinline__ u16x8 ldg16_sc(const unsigned short* p) {
  const u64t* q = (const u64t*)p;
  u64t a = __hip_atomic_load(q,     __ATOMIC_RELAXED, __HIP_MEMORY_SCOPE_AGENT);
  u64t b = __hip_atomic_load(q + 1, __ATOMIC_RELAXED, __HIP_MEMORY_SCOPE_AGENT);
  union { u64t d[2]; u16x8 v; } u; u.d[0] = a; u.d[1] = b; return u.v;
}
__device__ __forceinline__ void stg_h_sc(unsigned short* p, unsigned short v) {
  __hip_atomic_store(p, v, __ATOMIC_RELAXED, __HIP_MEMORY_SCOPE_AGENT);
}
__device__ __forceinline__ unsigned int ld_cnt(const unsigned int* p) {
  return __hip_atomic_load(p, __ATOMIC_RELAXED, __HIP_MEMORY_SCOPE_AGENT);
}
// wait until min over n progress words >= tgt (rigorous vs WG skew)
__device__ __forceinline__ void wait_min_ge(const unsigned int* base, int n, int tgt) {
  if (tgt <= 0) return;
  for (int it = 0; it < (1 << 16); ++it) {   // bounded: no hang on protocol bug
    unsigned int mn = 0xffffffffu;
    for (int i = 0; i < n; ++i) { unsigned int v = ld_cnt(base + i); mn = v < mn ? v : mn; }
    if (mn >= (unsigned int)tgt) return;
    __builtin_amdgcn_s_sleep(1);
  }
}
// publish own progress: caller is tid0 AFTER __syncthreads (all waves' stores drained)
__device__ __forceinline__ void publish(unsigned int* w, unsigned int v) {
  asm volatile("s_waitcnt vmcnt(0)" ::: "memory");
  __hip_atomic_store(w, v, __ATOMIC_RELAXED, __HIP_MEMORY_SCOPE_AGENT);
}

// ---------------- init: zero rings+counters, load hidden_state into "t=-1" slots ----------------
__global__ void __launch_bounds__(256) init_state(const float* __restrict__ hs, char* __restrict__ ws) {
  int g = blockIdx.x, tid = threadIdx.x;
  char* gb = ws + (size_t)g * GSTRIDE;
  // bulk zero whole group region (rings + counters)
  uint4 z4 = {0,0,0,0};
  for (int i = tid; i < (CNT_OFF + 256) / 16; i += 256) ((uint4*)gb)[i] = z4;
  __syncthreads();
  unsigned short* H0 = (unsigned short*)(gb + H0_OFF + (size_t)(D0-1)*H0_SLOT); // a_{-1} -> slot D0-1
  unsigned short* H1 = (unsigned short*)(gb + H1_OFF + (size_t)(D1-1)*H1_SLOT); // b_{-1} -> slot D1-1
  unsigned short* C2 = (unsigned short*)(gb + C2_OFF + (size_t)(D2-1)*C2_SLOT); // c_{-1} -> slot D2-1
  int b0 = g * MR;
  for (int i = tid; i < MR*H0N; i += 256) { int r = i/H0N, c = i%H0N; H0[r*H0P + c] = f2h_bits(hs[(size_t)(b0+r)*512 + c]); }
  for (int i = tid; i < MR*H1N; i += 256) { int r = i/H1N, c = i%H1N; H1[r*H1P + c] = f2h_bits(hs[(size_t)(b0+r)*512 + H0N + c]); }
  for (int i = tid; i < MR*64;  i += 256) { int r = i>>6,  c = i&63;  C2[r*64 + c]  = f2h_bits(hs[(size_t)(b0+r)*512 + 448 + c]); }
}

// ---------------- weight fragment builder (B operand, K x 16 tile) ----------------
template<int KK, int MODE>
__device__ __forceinline__ void build_frag(f16x8* wf, const float* __restrict__ W, const float* __restrict__ Msk,
                                           int h, int Kreal, int gate, int tile, int lane) {
  int col = tile * 16 + (lane & 15);
  bool nv = (col < h);
  #pragma unroll
  for (int kk = 0; kk < KK; ++kk) {
    f16x8 s;
    #pragma unroll
    for (int e = 0; e < 8; ++e) {
      int k = kk*32 + ((lane >> 4) << 3) + e;
      int wc;
      if (MODE == 0)      wc = (k < 333) ? k : -1;                                  // [x64|h269]
      else if (MODE == 1) wc = (k < 269) ? k : ((k >= 272 && k < 451) ? (k - 3) : -1);  // [a272|h1 192]
      else                wc = (k < 179) ? k : ((k >= 192 && k < 256) ? (k - 13) : -1); // [b192|c64]
      float val = 0.f;
      if (nv && wc >= 0) {
        val = W[(size_t)(gate * h + col) * Kreal + wc];
        if (gate < 2) val *= Msk[(size_t)col * Kreal + wc];
      }
      s[e] = (_Float16)val;
    }
    wf[kk] = s;
  }
}

__device__ __forceinline__ f16x8 lda(const unsigned short* xh, int stride, int mt, int kk, int lane) {
  const unsigned short* p = xh + (size_t)(mt*16 + (lane & 15)) * stride + kk*32 + ((lane >> 4) << 3);
  return __builtin_bit_cast(f16x8, *(const u16x8*)p);
}

// ---------------- one cell: MFMA all 4 gates (gate = wave), combine, write h_next ----------------
template<int KK, int NT>
__device__ __forceinline__ void cell_phase(const unsigned short* xh, int xstride,
    const f16x8 (&wf)[NT][KK], int ntact, const int* tids, int h,
    const float* biasL, unsigned short* Hnext, int hstride,
    float* zbuf, int lane, int wave, int tid) {
  #pragma unroll
  for (int it = 0; it < NT; ++it) {
    if (it < ntact) {
      f32x4 acc0 = {0.f,0.f,0.f,0.f}, acc1 = {0.f,0.f,0.f,0.f};
      #pragma unroll
      for (int kk = 0; kk < KK; ++kk) {
        f16x8 a0 = lda(xh, xstride, 0, kk, lane);
        f16x8 a1 = lda(xh, xstride, 1, kk, lane);
        acc0 = MFMA16(a0, wf[it][kk], acc0);
        acc1 = MFMA16(a1, wf[it][kk], acc1);
      }
      int colz = lane & 15, rb = (lane >> 4) * 4;
      #pragma unroll
      for (int r = 0; r < 4; ++r) {
        zbuf[(wave*32 + rb + r)*16 + colz]      = acc0[r];
        zbuf[(wave*32 + 16 + rb + r)*16 + colz] = acc1[r];
      }
    }
    __syncthreads();
    if (it < ntact) {
      int tile = tids[it];
      #pragma unroll
      for (int q = 0; q < 2; ++q) {
        int e = tid + q*256;
        int row = e >> 4, cc = e & 15;
        int n = tile*16 + cc;
        if (n < h) {
          float ff1 = zbuf[(0*32+row)*16+cc] + biasL[it*64 + cc];
          float ff2 = zbuf[(1*32+row)*16+cc] + biasL[it*64 + 16 + cc];
          float ta  = zbuf[(2*32+row)*16+cc] + biasL[it*64 + 32 + cc];
          float tb  = zbuf[(3*32+row)*16+cc] + biasL[it*64 + 48 + cc];
          float ti  = 1.f / (1.f + __expf(-(ta + tb)));
          float hv  = tanhf(ff1)*(1.f - ti) + ti*tanhf(ff2);
          stg_h_sc(&Hnext[(size_t)row*hstride + n], f2h_bits(hv));
        }
      }
    }
    __syncthreads();   // drains all waves' stores before any publish
  }
}

// ---------------- output projection for step t (waves 0,1 = row-tiles) ----------------
__device__ __forceinline__ void yproj_g(const unsigned short* Cb, const f16x8 (&wf)[2], float boutv,
                                        float* __restrict__ out, int b0, int t, int ytile, int lane, int wave) {
  if (wave > 1) return;
  int mt = wave;
  f32x4 acc = {0.f,0.f,0.f,0.f};
  #pragma unroll
  for (int kk = 0; kk < 2; ++kk) {
    f16x8 a = __builtin_bit_cast(f16x8, ldg16_sc(Cb + (size_t)(mt*16 + (lane & 15)) * 64 + kk*32 + ((lane >> 4) << 3)));
    acc = MFMA16(a, wf[kk], acc);
  }
  int cc = lane & 15, rb = (lane >> 4) * 4;
  #pragma unroll
  for (int r = 0; r < 4; ++r) {
    int row = mt*16 + rb + r;
    out[((size_t)(b0 + row) * LSEQ + t) * 64 + ytile*16 + cc] = acc[r] + boutv;
  }
}

// ---------------- persistent cascade kernel ----------------
// Per group (16 WGs): j=0..5 cell0 only (17 tiles: 3,3,3,3,3,2); j=6..11 cell1
// only (12 tiles: 2 each); j=12..15 cell2 (1 tile each) + y-proj (1 y-tile each,
// lagging 1 step). States in rings (H0,H1 depth 8; C2 depth 4) so each cell's
// recurrence carries exactly ONE cross-WG handshake per step; the three chains
// pipeline concurrently. Per-WG progress words (min-polled) — skew-rigorous.
// Dep graph (completion t requires): cell0@t <- {cell0@t-1, cell1@t-8(ring)};
// cell1@t <- {cell0@t, cell1@t-1, cell2@t-8(ring)};
// cell2@t <- {cell1@t, cell2w@t-1, cell2@t-4(ring)}. Acyclic -> deadlock-free.
__global__ void __launch_bounds__(256, 1) rnn_persist(
    const float* __restrict__ dt,
    const float* __restrict__ W0, const float* __restrict__ b0v,
    const float* __restrict__ W1, const float* __restrict__ b1v,
    const float* __restrict__ W2, const float* __restrict__ b2v,
    const float* __restrict__ Wout, const float* __restrict__ boutg,
    const float* __restrict__ M0, const float* __restrict__ M1, const float* __restrict__ M2,
    float* __restrict__ out, char* __restrict__ ws)
{
  __shared__ __attribute__((aligned(16))) unsigned short xh[MR * XH1S]; // 31232 B
  __shared__ __attribute__((aligned(16))) float zbuf[4 * MR * 16];      // 8 KB
  __shared__ float biasL[256];

  int tid = threadIdx.x;
  int lane = tid & 63, wave = tid >> 6;
  int bid = blockIdx.x;
  int xcd = bid & 7, slot = bid >> 3;        // bid%8 ~ XCD (perf heuristic only)
  int g = (xcd << 1) | (slot >> 4);
  int j = slot & 15;
  int b0 = g * MR;

  char* gb = ws + (size_t)g * GSTRIDE;
  unsigned short* H0r = (unsigned short*)(gb + H0_OFF);
  unsigned short* H1r = (unsigned short*)(gb + H1_OFF);
  unsigned short* C2r = (unsigned short*)(gb + C2_OFF);
  unsigned int* prog0 = (unsigned int*)(gb + CNT_OFF);        // 6 words
  unsigned int* prog1 = (unsigned int*)(gb + CNT_OFF + 64);   // 6 words
  unsigned int* c2w   = (unsigned int*)(gb + CNT_OFF + 128);  // 4 words (c written)
  unsigned int* prog2 = (unsigned int*)(gb + CNT_OFF + 192);  // 4 words (step incl. y)

  u16x8 zz = {0,0,0,0,0,0,0,0};

  if (j < 6) {
    // ================= cell0 =================
    int nt0 = (j < 5) ? 3 : 2;
    int t0ids[3] = { 3*j, 3*j + 1, 3*j + 2 };
    f16x8 w0f[3][KK0];
    build_frag<KK0,0>(w0f[0], W0, M0, H0N, K0REAL, wave, t0ids[0], lane);
    build_frag<KK0,0>(w0f[1], W0, M0, H0N, K0REAL, wave, t0ids[1], lane);
    if (nt0 == 3) build_frag<KK0,0>(w0f[2], W0, M0, H0N, K0REAL, wave, t0ids[2], lane);
    if (tid < 192) {
      int it = tid >> 6, gg = (tid >> 4) & 3, cc = tid & 15;
      float v = 0.f;
      if (it < nt0) { int n = t0ids[it]*16 + cc; if (n < H0N) v = b0v[gg*H0N + n]; }
      biasL[tid] = v;
    }
    // static k-pad (cols 336..351) once
    for (int idx = tid; idx < MR*2; idx += 256) {
      int r = idx >> 1, c8 = 336 + (idx & 1)*8;
      *(u16x8*)(xh + (size_t)r*XH0S + c8) = zz;
    }
    __syncthreads();
    for (int t = 0; t < LSEQ; ++t) {
      // stage x_t (independent of handshake) while waiting
      {
        int row = tid >> 3, c = (tid & 7) * 8;
        const float* src = dt + ((size_t)(b0 + row) * LSEQ + t) * 64 + c;
        float4 fa = *(const float4*)src;
        float4 fb = *(const float4*)(src + 4);
        unsigned short* d = xh + (size_t)row * XH0S + c;
        d[0]=f2h_bits(fa.x); d[1]=f2h_bits(fa.y); d[2]=f2h_bits(fa.z); d[3]=f2h_bits(fa.w);
        d[4]=f2h_bits(fb.x); d[5]=f2h_bits(fb.y); d[6]=f2h_bits(fb.z); d[7]=f2h_bits(fb.w);
      }
      if (tid == 0) {
        wait_min_ge(prog0, 6, t);                  // a_{t-1} complete
        wait_min_ge(prog1, 6, t - (D0 - 1));       // ring: readers of a_{t-D0} done
      }
      __syncthreads();
      { // stage a_{t-1} from ring
        const unsigned short* H0s = H0r + (size_t)((t + D0 - 1) & (D0 - 1)) * MR * H0P;
        for (int idx = tid; idx < MR*34; idx += 256) {
          int r = idx / 34, c8 = (idx % 34) * 8;
          *(u16x8*)(xh + (size_t)r*XH0S + 64 + c8) = ldg16_sc(H0s + (size_t)r*H0P + c8);
        }
      }
      __syncthreads();
      cell_phase<KK0,3>(xh, XH0S, w0f, nt0, t0ids, H0N, biasL,
                        H0r + (size_t)(t & (D0 - 1)) * MR * H0P, H0P, zbuf, lane, wave, tid);
      if (tid == 0) publish(&prog0[j], t + 1);
    }
  } else if (j < 12) {
    // ================= cell1 =================
    int i1 = j - 6;
    int t1ids[2] = { 2*i1, 2*i1 + 1 };
    f16x8 w1f[2][KK1];
    build_frag<KK1,1>(w1f[0], W1, M1, H1N, K1REAL, wave, t1ids[0], lane);
    build_frag<KK1,1>(w1f[1], W1, M1, H1N, K1REAL, wave, t1ids[1], lane);
    if (tid < 128) {
      int it = tid >> 6, gg = (tid >> 4) & 3, cc = tid & 15;
      int n = t1ids[it]*16 + cc;
      biasL[tid] = (n < H1N) ? b1v[gg*H1N + n] : 0.f;
    }
    for (int idx = tid; idx < MR*2; idx += 256) {   // k-pad 464..479 once
      int r = idx >> 1, c8 = 464 + (idx & 1)*8;
      *(u16x8*)(xh + (size_t)r*XH1S + c8) = zz;
    }
    __syncthreads();
    for (int t = 0; t < LSEQ; ++t) {
      if (tid == 0) {
        wait_min_ge(prog0, 6, t + 1);              // a_t ready
        wait_min_ge(prog1, 6, t);                  // b_{t-1} complete
        wait_min_ge(prog2, 4, t - (D1 - 1));       // ring: readers of b_{t-D1} done
      }
      __syncthreads();
      {
        const unsigned short* As = H0r + (size_t)(t & (D0 - 1)) * MR * H0P;
        const unsigned short* Bs = H1r + (size_t)((t + D1 - 1) & (D1 - 1)) * MR * H1P;
        for (int idx = tid; idx < MR*34; idx += 256) {
          int r = idx/34, c8 = (idx%34)*8;
          *(u16x8*)(xh + (size_t)r*XH1S + c8) = ldg16_sc(As + (size_t)r*H0P + c8);
        }
        for (int idx = tid; idx < MR*24; idx += 256) {
          int r = idx/24, c8 = (idx%24)*8;
          *(u16x8*)(xh + (size_t)r*XH1S + 272 + c8) = ldg16_sc(Bs + (size_t)r*H1P + c8);
        }
      }
      __syncthreads();
      cell_phase<KK1,2>(xh, XH1S, w1f, 2, t1ids, H1N, biasL,
                        H1r + (size_t)(t & (D1 - 1)) * MR * H1P, H1P, zbuf, lane, wave, tid);
      if (tid == 0) publish(&prog1[i1], t + 1);
    }
  } else {
    // ================= cell2 + y =================
    int i2 = j - 12;
    int t2ids[1] = { i2 };
    int ytile = i2;
    f16x8 w2f[1][KK2], woutf[2];
    build_frag<KK2,2>(w2f[0], W2, M2, H2N, K2REAL, wave, i2, lane);
    {
      int wcol = ytile*16 + (lane & 15);
      #pragma unroll
      for (int kk = 0; kk < 2; ++kk) {
        f16x8 s;
        #pragma unroll
        for (int e = 0; e < 8; ++e) {
          int k = kk*32 + ((lane >> 4) << 3) + e;
          s[e] = (_Float16)Wout[(size_t)wcol*64 + k];
        }
        woutf[kk] = s;
      }
    }
    float bov = boutg[ytile*16 + (lane & 15)];
    if (tid < 64) {
      int gg = (tid >> 4) & 3, cc = tid & 15;
      biasL[tid] = b2v[gg*H2N + i2*16 + cc];
    }
    __syncthreads();
    for (int t = 0; t < LSEQ; ++t) {
      if (tid == 0) {
        wait_min_ge(prog1, 6, t + 1);              // b_t ready
        wait_min_ge(c2w,   4, t);                  // c_{t-1} complete
        wait_min_ge(prog2, 4, t - (D2 - 1));       // ring: readers of c_{t-D2} done
      }
      __syncthreads();
      {
        const unsigned short* Bs = H1r + (size_t)(t & (D1 - 1)) * MR * H1P;
        const unsigned short* Cs = C2r + (size_t)((t + D2 - 1) & (D2 - 1)) * MR * 64;
        for (int idx = tid; idx < MR*24; idx += 256) {
          int r = idx/24, c8 = (idx%24)*8;
          *(u16x8*)(xh + (size_t)r*XH2S + c8) = ldg16_sc(Bs + (size_t)r*H1P + c8);
        }
        for (int idx = tid; idx < MR*8; idx += 256) {
          int r = idx >> 3, c8 = (idx & 7)*8;
          *(u16x8*)(xh + (size_t)r*XH2S + 192 + c8) = ldg16_sc(Cs + (size_t)r*64 + c8);
        }
      }
      __syncthreads();
      // y_{t-1} (c_{t-1} already guaranteed by c2w >= t wait)
      if (t > 0)
        yproj_g(C2r + (size_t)((t + D2 - 1) & (D2 - 1)) * MR * 64, woutf, bov, out, b0, t - 1, ytile, lane, wave);
      cell_phase<KK2,1>(xh, XH2S, w2f, 1, t2ids, H2N, biasL,
                        C2r + (size_t)(t & (D2 - 1)) * MR * 64, 64, zbuf, lane, wave, tid);
      if (tid == 0) {
        publish(&c2w[i2], t + 1);
        publish(&prog2[i2], t + 1);
      }
    }
    // tail: y_{255}
    if (tid == 0) wait_min_ge(c2w, 4, LSEQ);
    __syncthreads();
    yproj_g(C2r + (size_t)((LSEQ - 1) & (D2 - 1)) * MR * 64, woutf, bov, out, b0, LSEQ - 1, ytile, lane, wave);
  }
}

extern "C" void kernel_launch(void* const* d_in, const int* in_sizes, int n_in,
                              void* d_out, int out_size, void* d_ws, size_t ws_size,
                              hipStream_t stream) {
  const float* dt   = (const float*)d_in[0];
  const float* hs   = (const float*)d_in[1];
  const float* W0   = (const float*)d_in[2];
  const float* b0v  = (const float*)d_in[3];
  const float* W1   = (const float*)d_in[4];
  const float* b1v  = (const float*)d_in[5];
  const float* W2   = (const float*)d_in[6];
  const float* b2v  = (const float*)d_in[7];
  const float* Wo   = (const float*)d_in[8];
  const float* bo   = (const float*)d_in[9];
  const float* M0   = (const float*)d_in[10];
  const float* M1   = (const float*)d_in[11];
  const float* M2   = (const float*)d_in[12];
  (void)in_sizes; (void)n_in; (void)out_size; (void)ws_size;
  init_state<<<16, 256, 0, stream>>>(hs, (char*)d_ws);
  rnn_persist<<<256, 256, 0, stream>>>(dt, W0, b0v, W1, b1v, W2, b2v, Wo, bo, M0, M1, M2,
                                       (float*)d_out, (char*)d_ws);
}